// Round 9
// baseline (387.104 us; speedup 1.0000x reference)
//
#include <hip/hip_runtime.h>
#include <math.h>

// MoLoRARouter: logits = x[16384,4096] @ gate_w[64,4096]^T (fp32) -> softmax
// -> top-2 -> renorm.  fp32 emulated as split-2 fp16 MFMA:
//   v = h + l/2048,  h = fp16(v), l = fp16((v-h)*2048)   (~22-24 mantissa bits)
//   logit = hh + (hl+lh)/2048 + ll/2048^2  -> error ~1e-6, fp32-reorder class.
//
// V8: router ~123us vs 43us HBM floor ≈ SUM of {HBM 43, cvt-VALU 17 (4x
// redundant), B-L2 30, LDS 17} -> remove work, not reshuffle it:
//  - BM=32: B-L2 traffic halves; per-token step overhead halves.
//  - convert-once: raw x staged HBM->LDS 3-ahead (global_load_lds, 3 bufs);
//    each wave stages AND converts only its own 8 rows (no cross-wave raw
//    hazards) into split-fp16 LDS tiles; MFMA reads half8 directly. 4x less
//    conversion VALU, and cvt co-schedules with MFMA in the same phase.
//  - ONE raw barrier per step: vmcnt(8) counted (st(kt+2),st(kt+3),B(kt+1)
//    stay in flight) + lgkmcnt(0) + s_barrier. Convert writes split[nxt],
//    compute reads split[cur] -> no conflict inside the phase.
//  - LDS 42 KB -> 3 blocks/CU; launch_bounds(256,3) -> no spill (~110 VGPR).

typedef _Float16 half8 __attribute__((ext_vector_type(8)));
typedef float floatx4 __attribute__((ext_vector_type(4)));

constexpr int Hdim = 4096;
constexpr int Edim = 64;
constexpr int NTOK = 16384;
constexpr int BM   = 32;           // tokens per block
constexpr int BK   = 64;           // K floats per tile
constexpr int NKT  = Hdim / BK;    // 64 steps (pow2)
constexpr float SCL  = 2048.0f;
constexpr float ISCL = 1.0f / 2048.0f;

// split-w, fragment-major, module device memory (fill is unconditional, but
// module globals avoid any workspace interaction):
__device__ alignas(16) _Float16 g_whf[(size_t)Edim * Hdim];
__device__ alignas(16) _Float16 g_wlf[(size_t)Edim * Hdim];

#define GLD_LDS16(gp, lp)                                              \
    __builtin_amdgcn_global_load_lds(                                  \
        (const __attribute__((address_space(1))) void*)(gp),           \
        (__attribute__((address_space(3))) void*)(lp), 16, 0, 0)

// ---- pre-kernel: gate_w fp32 -> split fp16, fragment-major ----
// Fragment (kc = k/32 in [0,128), nt in [0,4), lane in [0,64)):
//   value = w[nt*16 + (lane&15)][kc*32 + (lane>>4)*8 + j], j=0..7
//   stored at wf[((kc*4 + nt)*64 + lane)*8 + j]
__global__ __launch_bounds__(256)
void wconv_kernel(const float* __restrict__ gw)
{
    const int n    = blockIdx.x * 256 + threadIdx.x;   // 0..32767
    const int lane = n & 63;
    const int frag = n >> 6;           // 0..511
    const int nt   = frag & 3;
    const int kc   = frag >> 2;        // 0..127
    const int e    = nt * 16 + (lane & 15);
    const int k0   = kc * 32 + (lane >> 4) * 8;

    const float* src = gw + (size_t)e * Hdim + k0;
    const float4 v0 = *(const float4*)src;
    const float4 v1 = *(const float4*)(src + 4);
    const float* p0 = (const float*)&v0;
    const float* p1 = (const float*)&v1;
    half8 h, l;
    #pragma unroll
    for (int c = 0; c < 4; ++c) {
        _Float16 hh = (_Float16)p0[c];
        h[c] = hh;
        l[c] = (_Float16)((p0[c] - (float)hh) * SCL);
        hh = (_Float16)p1[c];
        h[c + 4] = hh;
        l[c + 4] = (_Float16)((p1[c] - (float)hh) * SCL);
    }
    *(half8*)(g_whf + (size_t)n * 8) = h;
    *(half8*)(g_wlf + (size_t)n * 8) = l;
}

// ---- main kernel: block = 32 tokens, 4 waves; wave w = experts [16w,16w+16) ----
__global__ __launch_bounds__(256, 3)
void router_kernel(const float* __restrict__ x,
                   float* __restrict__ out)
{
    // raw x: [32 rows][16 granules of 16B], slot = g ^ (row&7). 8 KiB x 3.
    __shared__ alignas(16) float    sraw[3][BM * BK];
    // split x: [32 rows][8 granules of 8 halves], slot = g ^ (row&7). 4 KiB x 2 each.
    __shared__ alignas(16) _Float16 sxh[2][BM * BK];
    __shared__ alignas(16) _Float16 sxl[2][BM * BK];
    __shared__ alignas(16) float4   sc[4][BM];   // per-wave top-2 candidates

    const int tid  = threadIdx.x;
    const int w    = tid >> 6;
    const int lane = tid & 63;
    const int ln15 = lane & 15;
    const int quad = lane >> 4;
    const int t0   = blockIdx.x * BM;

    // staging: wave w stages rows [8w,8w+8); instr p covers rows 8w+4p..+3.
    // lane -> row = 8w + 4p + (lane>>4), LDS slot = lane&15 (linear),
    // global granule = (lane&15) ^ (row&7)  (pre-swizzled source, rule #21)
    const int r0  = 8 * w + (lane >> 4);
    const int r1  = r0 + 4;
    const int gg0 = (lane & 15) ^ (r0 & 7);
    const int gg1 = (lane & 15) ^ (r1 & 7);
    const float* px0 = x + (size_t)(t0 + r0) * Hdim + gg0 * 4;
    const float* px1 = x + (size_t)(t0 + r1) * Hdim + gg1 * 4;

    // convert: wave w converts ONLY its own rows [8w,8w+8):
    // row = 8w + ((tid>>3)&7), col-chunk cc = tid&7 (8 floats)
    const int cr  = 8 * w + ((tid >> 3) & 7);
    const int cc  = tid & 7;
    const int crs = cr & 7;
    const int rdA = cr * BK + (((2 * cc)     ^ crs) << 2);  // raw granules (4 floats)
    const int rdB = cr * BK + (((2 * cc + 1) ^ crs) << 2);
    const int wrS = cr * BK + ((cc ^ crs) << 3);            // split granule (8 halves)

    // B: fragment-major, this wave's expert slice nt=w
    const _Float16* whw = g_whf + (size_t)w * 512 + lane * 8;
    const _Float16* wlw = g_wlf + (size_t)w * 512 + lane * 8;

    floatx4 accm[2], accc[2], accl[2];
    #pragma unroll
    for (int mt = 0; mt < 2; ++mt) {
        accm[mt] = (floatx4)0.0f;
        accc[mt] = (floatx4)0.0f;
        accl[mt] = (floatx4)0.0f;
    }

    auto cvt8 = [&](const float4& a, const float4& b, half8& h, half8& l) {
        const float* pa = (const float*)&a;
        const float* pb = (const float*)&b;
        #pragma unroll
        for (int c = 0; c < 4; ++c) {
            _Float16 hh = (_Float16)pa[c];
            h[c] = hh;
            l[c] = (_Float16)((pa[c] - (float)hh) * SCL);
            hh = (_Float16)pb[c];
            h[c + 4] = hh;
            l[c + 4] = (_Float16)((pb[c] - (float)hh) * SCL);
        }
    };

    // convert tile (raw buf rb) -> split buf sb, own rows only
    auto convert = [&](int rb, int sb) {
        const float4 f0 = *(const float4*)&sraw[rb][rdA];
        const float4 f1 = *(const float4*)&sraw[rb][rdB];
        half8 h, l;
        cvt8(f0, f1, h, l);
        *(half8*)&sxh[sb][wrS] = h;
        *(half8*)&sxl[sb][wrS] = l;
    };

    half8 bhA[2], blA[2], bhB[2], blB[2];   // B double-buffer, static names

    // ---- prologue: issue st0, st1, B(0), st2; wait st0; convert tile 0 ----
    GLD_LDS16(px0 + 0 * BK, &sraw[0][(8 * w) * BK]);
    GLD_LDS16(px1 + 0 * BK, &sraw[0][(8 * w + 4) * BK]);
    GLD_LDS16(px0 + 1 * BK, &sraw[1][(8 * w) * BK]);
    GLD_LDS16(px1 + 1 * BK, &sraw[1][(8 * w + 4) * BK]);
    #pragma unroll
    for (int c = 0; c < 2; ++c) {
        bhA[c] = *(const half8*)(whw + (size_t)c * 2048);
        blA[c] = *(const half8*)(wlw + (size_t)c * 2048);
    }
    GLD_LDS16(px0 + 2 * BK, &sraw[2][(8 * w) * BK]);
    GLD_LDS16(px1 + 2 * BK, &sraw[2][(8 * w + 4) * BK]);

    asm volatile("s_waitcnt vmcnt(8)" ::: "memory");  // st0 done (own rows)
    convert(0, 0);

    // one pipeline step: compute tile kt with bc*, prefetch B(kt+1) into bn*
    auto step = [&](int kt, half8 (&bch)[2], half8 (&bcl)[2],
                            half8 (&bnh)[2], half8 (&bnl)[2]) {
        // issue next-step B prefetch (pinned between asm memory clobbers)
        const int ktn = (kt + 1) & (NKT - 1);
        #pragma unroll
        for (int c = 0; c < 2; ++c) {
            bnh[c] = *(const half8*)(whw + (size_t)(2 * ktn + c) * 2048);
            bnl[c] = *(const half8*)(wlw + (size_t)(2 * ktn + c) * 2048);
        }
        // 3-ahead stage: tile (kt+3) into raw buf (kt+3)%3 (own rows; that buf
        // held tile kt, converted by this wave at step kt-1 -> safe)
        const int ts = (kt + 3) & (NKT - 1);
        const int tb = (kt + 3) % 3;
        GLD_LDS16(px0 + (size_t)ts * BK, &sraw[tb][(8 * w) * BK]);
        GLD_LDS16(px1 + (size_t)ts * BK, &sraw[tb][(8 * w + 4) * BK]);

        // counted wait: completes st(kt+1) + B(kt); keeps st(kt+2), B(kt+1),
        // st(kt+3) in flight.  lgkm0 retires our ds ops; barrier publishes.
        asm volatile("s_waitcnt vmcnt(8)" ::: "memory");
        asm volatile("s_waitcnt lgkmcnt(0)" ::: "memory");
        __builtin_amdgcn_sched_barrier(0);
        asm volatile("s_barrier" ::: "memory");

        // convert tile kt+1 (own rows) while computing tile kt (all rows)
        convert((kt + 1) % 3, (kt + 1) & 1);

        const int cb = kt & 1;
        #pragma unroll
        for (int c = 0; c < 2; ++c) {
            #pragma unroll
            for (int mt = 0; mt < 2; ++mt) {
                const int row = mt * 16 + ln15;
                const int sA  = row * BK + (((c * 4 + quad) ^ (row & 7)) << 3);
                const half8 ah = *(const half8*)&sxh[cb][sA];
                const half8 al = *(const half8*)&sxl[cb][sA];
                accm[mt] = __builtin_amdgcn_mfma_f32_16x16x32_f16(ah, bch[c], accm[mt], 0, 0, 0);
                accc[mt] = __builtin_amdgcn_mfma_f32_16x16x32_f16(ah, bcl[c], accc[mt], 0, 0, 0);
                accc[mt] = __builtin_amdgcn_mfma_f32_16x16x32_f16(al, bch[c], accc[mt], 0, 0, 0);
                accl[mt] = __builtin_amdgcn_mfma_f32_16x16x32_f16(al, bcl[c], accl[mt], 0, 0, 0);
            }
        }
    };

    for (int kt = 0; kt < NKT; kt += 2) {
        step(kt,     bhA, blA, bhB, blB);
        step(kt + 1, bhB, blB, bhA, blA);
    }
    __syncthreads();   // drain dummies; publish nothing-else; sync before sc

    // ---- epilogue: combine split terms; top-2 ----
    // D layout: token = mt*16 + quad*4 + i, expert = w*16 + ln15.
    #pragma unroll
    for (int mt = 0; mt < 2; ++mt) {
        const floatx4 vv = accm[mt] + accc[mt] * ISCL + accl[mt] * (ISCL * ISCL);
        #pragma unroll
        for (int i = 0; i < 4; ++i) {
            float m1 = vv[i], m2 = -INFINITY;
            int i1 = w * 16 + ln15, i2 = 0;
            #pragma unroll
            for (int mk = 1; mk <= 8; mk <<= 1) {   // 16-lane butterfly
                const float om1 = __shfl_xor(m1, mk);
                const int   oi1 = __shfl_xor(i1, mk);
                const float om2 = __shfl_xor(m2, mk);
                const int   oi2 = __shfl_xor(i2, mk);
                const bool aw = (m1 > om1) || (m1 == om1 && i1 < oi1);
                const float w1v = aw ? m1 : om1;  const int w1i = aw ? i1 : oi1;
                const float ca  = aw ? m2 : om2;  const int cai = aw ? i2 : oi2;
                const float cb  = aw ? om1 : m1;  const int cbi = aw ? oi1 : i1;
                const bool sw2 = (ca > cb) || (ca == cb && cai < cbi);
                m1 = w1v; i1 = w1i;
                m2 = sw2 ? ca : cb;
                i2 = sw2 ? cai : cbi;
            }
            if (ln15 == 0)
                sc[w][mt * 16 + quad * 4 + i] = float4{m1, m2, (float)i1, (float)i2};
        }
    }
    __syncthreads();

    if (tid < BM) {   // merge the 4 expert-slice candidates per token
        float4 c = sc[0][tid];
        float m1 = c.x, m2 = c.y, i1 = c.z, i2 = c.w;
        #pragma unroll
        for (int q = 1; q < 4; ++q) {
            c = sc[q][tid];
            const float om1 = c.x, om2 = c.y, oi1 = c.z, oi2 = c.w;
            const bool aw = (m1 > om1) || (m1 == om1 && i1 < oi1);
            const float w1v = aw ? m1 : om1;  const float w1i = aw ? i1 : oi1;
            const float ca  = aw ? m2 : om2;  const float cai = aw ? i2 : oi2;
            const float cb  = aw ? om1 : m1;  const float cbi = aw ? oi1 : i1;
            const bool sw2 = (ca > cb) || (ca == cb && cai < cbi);
            m1 = w1v; i1 = w1i;
            m2 = sw2 ? ca : cb;
            i2 = sw2 ? cai : cbi;
        }
        const float r   = expf(m2 - m1);
        const float inv = 1.0f / (1.0f + r);
        const int t = t0 + tid;
        float* ow = out + 2 * (size_t)t;
        ow[0] = inv;
        ow[1] = r * inv;
        float* oi = out + 2 * (size_t)NTOK + 2 * (size_t)t;
        oi[0] = i1;
        oi[1] = i2;
    }
}

extern "C" void kernel_launch(void* const* d_in, const int* in_sizes, int n_in,
                              void* d_out, int out_size, void* d_ws, size_t ws_size,
                              hipStream_t stream) {
    const float* x  = (const float*)d_in[0];   // [4,4096,4096] fp32
    const float* gw = (const float*)d_in[1];   // [64,4096] fp32
    float* out = (float*)d_out;                // weights(32768) ++ indices(32768)
    (void)d_ws; (void)ws_size;

    hipLaunchKernelGGL(wconv_kernel, dim3(128), dim3(256), 0, stream, gw);
    hipLaunchKernelGGL(router_kernel, dim3(NTOK / BM), dim3(256), 0, stream,
                       x, out);
}